// Round 4
// baseline (183.806 us; speedup 1.0000x reference)
//
#include <hip/hip_runtime.h>
#include <hip/hip_cooperative_groups.h>

namespace cg = cooperative_groups;

#define Bv 32
#define Av 3
#define Gv 52
#define Cv 80
#define Nv 512
#define Mv (Bv*Av*Gv*Gv)   // 259584
#define NBLK 256
#define NTHR 256

// fast ln with the reference's clip(log, -100)
__device__ __forceinline__ float flog(float x) {
    return fmaxf(__logf(x), -100.0f);
}

__device__ __forceinline__ float wred(float v) {
    #pragma unroll
    for (int o = 32; o > 0; o >>= 1) v += __shfl_down(v, o, 64);
    return v;   // valid on lane 0 of each wave
}

// partials layout per block (stride 16 floats):
// 0:bulk_noobj_sum 1:lx 2:ly 3:lw 4:lh 5:conf_obj 6:cls_corr 7:conf_sub
// 8:cls_base 9:n_obj 10:n_kill

__device__ __forceinline__ void decode_target(
    const float* __restrict__ tp, const float* s_anc,
    int& cell, int& pairkey, int kk[3], int& best_out,
    float& gx, float& gy, float& gw, float& gh)
{
    gx = tp[2] * Gv; gy = tp[3] * Gv; gw = tp[4] * Gv; gh = tp[5] * Gv;
    int si  = (int)tp[0];
    int lab = (int)tp[1];
    int gi = (int)floorf(gx), gj = (int)floorf(gy);
    float iou[3];
    #pragma unroll
    for (int a = 0; a < 3; ++a) {
        float aw = s_anc[2*a], ah = s_anc[2*a+1];
        float inter = fminf(aw, gw) * fminf(ah, gh);
        float uni = aw*ah + 1e-16f + gw*gh - inter;
        iou[a] = inter / uni;
    }
    int best = 0; float bi = iou[0];
    if (iou[1] > bi) { best = 1; bi = iou[1]; }
    if (iou[2] > bi) { best = 2; bi = iou[2]; }
    best_out = best;
    cell = ((si*Av + best)*Gv + gj)*Gv + gi;
    pairkey = cell * Cv + lab;
    #pragma unroll
    for (int a = 0; a < 3; ++a) {
        bool kill = (a == best) || (iou[a] > 0.5f);
        kk[a] = kill ? ((((si*Av + a)*Gv + gj)*Gv + gi) + 1) : 0;
    }
}

__global__ __launch_bounds__(NTHR) void fused_kernel(
    const float* __restrict__ pred_cls,
    const float* __restrict__ center_x,
    const float* __restrict__ center_y,
    const float* __restrict__ width_,
    const float* __restrict__ height_,
    const float* __restrict__ confidence,
    const float* __restrict__ anchors,
    const float* __restrict__ target,
    float* __restrict__ partials,
    float* __restrict__ out)
{
    __shared__ float s_targ[Nv * 6];   // 12 KB staged copy of target
    __shared__ int   s_cell[Nv];
    __shared__ int   s_pair[Nv];
    __shared__ int   s_kill[3*Nv];
    __shared__ int   s_flag[12];     // [0,1] rep blocked; [2,3] pair blocked; [4..9] kill blocked (j*3+a)
    __shared__ int   s_repcell[2];
    __shared__ float s_acc[11];
    __shared__ float s_anc[6];

    const int t = threadIdx.x;
    if (t < 6)  s_anc[t]  = anchors[t];
    if (t < 12) s_flag[t] = 0;
    if (t < 11) s_acc[t]  = 0.f;

    // ---- coalesced stage of target into LDS ----
    #pragma unroll
    for (int i = 0; i < (Nv*6)/NTHR; ++i)
        s_targ[i * NTHR + t] = target[i * NTHR + t];
    __syncthreads();

    // ---- redundant decode of all 512 targets into LDS tables (2 per thread) ----
    for (int n = t; n < Nv; n += NTHR) {
        int cell, pair, kk[3], best; float gx, gy, gw, gh;
        decode_target(s_targ + n*6, s_anc, cell, pair, kk, best, gx, gy, gw, gh);
        s_cell[n] = cell;
        s_pair[n] = pair;
        s_kill[3*n+0] = kk[0]; s_kill[3*n+1] = kk[1]; s_kill[3*n+2] = kk[2];
    }
    __syncthreads();

    // ---- dedup scan for this block's two owned targets ----
    const int n0 = 2 * blockIdx.x;          // owns n0, n0+1
    const int c0 = s_cell[n0],   c1 = s_cell[n0+1];
    const int p0 = s_pair[n0],   p1 = s_pair[n0+1];
    int k0[3], k1[3];
    #pragma unroll
    for (int a = 0; a < 3; ++a) { k0[a] = s_kill[3*n0+a]; k1[a] = s_kill[3*n0+3+a]; }

    for (int m = t; m < Nv; m += NTHR) {
        int cm = s_cell[m];
        if (m > n0     && cm == c0) s_flag[0] = 1;   // rep = max-n (last .set wins)
        if (m > n0 + 1 && cm == c1) s_flag[1] = 1;
        int pm = s_pair[m];
        if (m < n0     && pm == p0) s_flag[2] = 1;   // pair handled by min-n
        if (m < n0 + 1 && pm == p1) s_flag[3] = 1;
        #pragma unroll
        for (int a = 0; a < 3; ++a) {
            int km = s_kill[3*m + a];
            if (!km) continue;
            int idx = 3*m + a;
            #pragma unroll
            for (int a2 = 0; a2 < 3; ++a2) {
                if (idx < 3*n0 + a2     && km == k0[a2]) s_flag[4 + a2] = 1;
                if (idx < 3*(n0+1) + a2 && km == k1[a2]) s_flag[7 + a2] = 1;
            }
        }
    }
    __syncthreads();

    // ---- owned-target contributions (thread 0 -> n0, thread 64 -> n0+1) ----
    if (t == 0 || t == 64) {
        const int j = t >> 6;
        const int n = n0 + j;
        int cell, pair, kk[3], best; float gx, gy, gw, gh;
        decode_target(s_targ + n*6, s_anc, cell, pair, kk, best, gx, gy, gw, gh);

        int repv = 0;
        if (!s_flag[j]) {                       // I'm this cell's representative
            float tx = gx - floorf(gx);
            float ty = gy - floorf(gy);
            float tw = __logf(gw / s_anc[2*best]   + 1e-16f);
            float th = __logf(gh / s_anc[2*best+1] + 1e-16f);
            float dx = center_x[cell] - tx;
            float dy = center_y[cell] - ty;
            float dw = width_[cell]  - tw;
            float dh = height_[cell] - th;
            atomicAdd(&s_acc[1], dx*dx);
            atomicAdd(&s_acc[2], dy*dy);
            atomicAdd(&s_acc[3], dw*dw);
            atomicAdd(&s_acc[4], dh*dh);
            atomicAdd(&s_acc[5], -flog(confidence[cell]));
            atomicAdd(&s_acc[9], 1.f);          // n_obj
            repv = 1;
        }
        s_repcell[j] = repv ? cell : -1;

        if (!s_flag[2 + j]) {                   // first occurrence of (cell,label)
            float p = pred_cls[(size_t)pair];
            atomicAdd(&s_acc[6], -flog(p) + flog(1.f - p));
        }

        float csub = 0.f, nk = 0.f;
        #pragma unroll
        for (int a = 0; a < 3; ++a) {
            int kc = kk[a];
            if (kc && !s_flag[4 + 3*j + a]) {   // first occurrence of killed cell
                csub += -flog(1.f - confidence[kc - 1]);
                nk += 1.f;
            }
        }
        if (nk != 0.f) { atomicAdd(&s_acc[7], csub); atomicAdd(&s_acc[10], nk); }
    }
    __syncthreads();

    // ---- cls base for owned representative cells (80 classes each) ----
    {
        const int j = t >> 7;                   // threads 0-127 -> rep0, 128-255 -> rep1
        const int c = t & 127;
        float v = 0.f;
        int cell = s_repcell[j];
        if (cell >= 0 && c < Cv)
            v = -flog(1.f - pred_cls[(size_t)cell * Cv + c]);
        v = wred(v);
        if ((t & 63) == 0) atomicAdd(&s_acc[8], v);
    }

    // ---- bulk: sum of -clip(log(1-conf)) over ALL cells ----
    {
        float local = 0.f;
        const float4* c4 = (const float4*)confidence;
        for (int i = blockIdx.x * NTHR + t; i < Mv/4; i += NBLK * NTHR) {
            float4 v = c4[i];
            local -= flog(1.f - v.x) + flog(1.f - v.y) + flog(1.f - v.z) + flog(1.f - v.w);
        }
        local = wred(local);
        if ((t & 63) == 0) atomicAdd(&s_acc[0], local);
    }
    __syncthreads();

    // ---- publish this block's partials with agent-scope stores (XCD-safe) ----
    if (t < 11)
        __hip_atomic_store(&partials[blockIdx.x * 16 + t], s_acc[t],
                           __ATOMIC_RELEASE, __HIP_MEMORY_SCOPE_AGENT);

    cg::this_grid().sync();

    // ---- block 0 reduces 256 partial rows and writes the scalar ----
    if (blockIdx.x == 0) {
        __shared__ float s_r[4][11];
        float v[11];
        #pragma unroll
        for (int j = 0; j < 11; ++j)
            v[j] = __hip_atomic_load(&partials[t * 16 + j],
                                     __ATOMIC_ACQUIRE, __HIP_MEMORY_SCOPE_AGENT);
        #pragma unroll
        for (int j = 0; j < 11; ++j) v[j] = wred(v[j]);
        const int lane = t & 63, w = t >> 6;
        if (lane == 0) {
            #pragma unroll
            for (int j = 0; j < 11; ++j) s_r[w][j] = v[j];
        }
        __syncthreads();
        if (t == 0) {
            float a[11];
            #pragma unroll
            for (int j = 0; j < 11; ++j)
                a[j] = s_r[0][j] + s_r[1][j] + s_r[2][j] + s_r[3][j];
            float n_obj   = a[9];
            float n_kill  = a[10];
            float inv_obj = 1.f / n_obj;
            float n_noobj = (float)Mv - n_kill;
            float loss_coord = (a[1] + a[2] + a[3] + a[4]) * inv_obj;
            float loss_conf  = a[5] * inv_obj + 100.f * (a[0] - a[7]) / n_noobj;
            float loss_cls   = (a[8] + a[6]) * inv_obj / (float)Cv;
            out[0] = loss_coord + loss_conf + loss_cls;
        }
    }
}

extern "C" void kernel_launch(void* const* d_in, const int* in_sizes, int n_in,
                              void* d_out, int out_size, void* d_ws, size_t ws_size,
                              hipStream_t stream) {
    // setup_inputs order: 0:pred_boxes(unused) 1:pred_cls 2:center_x 3:center_y
    //                     4:width 5:height 6:confidence 7:anchors 8:target
    const float* pred_cls   = (const float*)d_in[1];
    const float* center_x   = (const float*)d_in[2];
    const float* center_y   = (const float*)d_in[3];
    const float* width_     = (const float*)d_in[4];
    const float* height_    = (const float*)d_in[5];
    const float* confidence = (const float*)d_in[6];
    const float* anchors    = (const float*)d_in[7];
    const float* target     = (const float*)d_in[8];
    float* partials = (float*)d_ws;   // 256 blocks × 16 floats = 16 KB
    float* outp     = (float*)d_out;

    void* args[] = { (void*)&pred_cls, (void*)&center_x, (void*)&center_y,
                     (void*)&width_, (void*)&height_, (void*)&confidence,
                     (void*)&anchors, (void*)&target, (void*)&partials,
                     (void*)&outp };
    hipLaunchCooperativeKernel((void*)fused_kernel, dim3(NBLK), dim3(NTHR),
                               args, 0, stream);
}

// Round 5
// 130.173 us; speedup vs baseline: 1.4120x; 1.4120x over previous
//
#include <hip/hip_runtime.h>

#define Bv 32
#define Av 3
#define Gv 52
#define Cv 80
#define Nv 512
#define Mv (Bv*Av*Gv*Gv)   // 259584
#define NBLK 256
#define NTHR 256
#define SENT_BASE 0x5A5A0000

// fast ln with the reference's clip(log, -100)
__device__ __forceinline__ float flog(float x) {
    return fmaxf(__logf(x), -100.0f);
}

__device__ __forceinline__ float wred(float v) {
    #pragma unroll
    for (int o = 32; o > 0; o >>= 1) v += __shfl_down(v, o, 64);
    return v;   // valid on lane 0 of each wave
}

// partials layout per block (stride 16 floats):
// 0:bulk_noobj_sum 1:lx 2:ly 3:lw 4:lh 5:conf_obj 6:cls_corr 7:conf_sub
// 8:cls_base 9:n_obj 10:n_kill 11:sentinel(int)

__device__ __forceinline__ void decode_target(
    const float* __restrict__ tp, const float* s_anc,
    int& cell, int& pairkey, int kk[3], int& best_out,
    float& gx, float& gy, float& gw, float& gh)
{
    gx = tp[2] * Gv; gy = tp[3] * Gv; gw = tp[4] * Gv; gh = tp[5] * Gv;
    int si  = (int)tp[0];
    int lab = (int)tp[1];
    int gi = (int)floorf(gx), gj = (int)floorf(gy);
    float iou[3];
    #pragma unroll
    for (int a = 0; a < 3; ++a) {
        float aw = s_anc[2*a], ah = s_anc[2*a+1];
        float inter = fminf(aw, gw) * fminf(ah, gh);
        float uni = aw*ah + 1e-16f + gw*gh - inter;
        iou[a] = inter / uni;
    }
    int best = 0; float bi = iou[0];
    if (iou[1] > bi) { best = 1; bi = iou[1]; }
    if (iou[2] > bi) { best = 2; bi = iou[2]; }
    best_out = best;
    cell = ((si*Av + best)*Gv + gj)*Gv + gi;
    pairkey = cell * Cv + lab;
    #pragma unroll
    for (int a = 0; a < 3; ++a) {
        bool kill = (a == best) || (iou[a] > 0.5f);
        kk[a] = kill ? ((((si*Av + a)*Gv + gj)*Gv + gi) + 1) : 0;
    }
}

__global__ __launch_bounds__(NTHR) void fused_kernel(
    const float* __restrict__ pred_cls,
    const float* __restrict__ center_x,
    const float* __restrict__ center_y,
    const float* __restrict__ width_,
    const float* __restrict__ height_,
    const float* __restrict__ confidence,
    const float* __restrict__ anchors,
    const float* __restrict__ target,
    float* __restrict__ partials,
    float* __restrict__ out)
{
    __shared__ float s_targ[Nv * 6];   // 12 KB staged copy of target
    __shared__ int   s_cell[Nv];
    __shared__ int   s_pair[Nv];
    __shared__ int   s_kill[3*Nv];
    __shared__ int   s_flag[12];     // [0,1] rep blocked; [2,3] pair blocked; [4..9] kill blocked (j*3+a)
    __shared__ int   s_repcell[2];
    __shared__ float s_acc[11];
    __shared__ float s_anc[6];

    const int t = threadIdx.x;
    if (t < 6)  s_anc[t]  = anchors[t];
    if (t < 12) s_flag[t] = 0;
    if (t < 11) s_acc[t]  = 0.f;

    // ---- coalesced stage of target into LDS ----
    #pragma unroll
    for (int i = 0; i < (Nv*6)/NTHR; ++i)
        s_targ[i * NTHR + t] = target[i * NTHR + t];
    __syncthreads();

    // ---- redundant decode of all 512 targets into LDS tables (2 per thread) ----
    for (int n = t; n < Nv; n += NTHR) {
        int cell, pair, kk[3], best; float gx, gy, gw, gh;
        decode_target(s_targ + n*6, s_anc, cell, pair, kk, best, gx, gy, gw, gh);
        s_cell[n] = cell;
        s_pair[n] = pair;
        s_kill[3*n+0] = kk[0]; s_kill[3*n+1] = kk[1]; s_kill[3*n+2] = kk[2];
    }
    __syncthreads();

    // ---- dedup scan for this block's two owned targets ----
    const int n0 = 2 * blockIdx.x;          // owns n0, n0+1
    const int c0 = s_cell[n0],   c1 = s_cell[n0+1];
    const int p0 = s_pair[n0],   p1 = s_pair[n0+1];
    int k0[3], k1[3];
    #pragma unroll
    for (int a = 0; a < 3; ++a) { k0[a] = s_kill[3*n0+a]; k1[a] = s_kill[3*n0+3+a]; }

    for (int m = t; m < Nv; m += NTHR) {
        int cm = s_cell[m];
        if (m > n0     && cm == c0) s_flag[0] = 1;   // rep = max-n (last .set wins)
        if (m > n0 + 1 && cm == c1) s_flag[1] = 1;
        int pm = s_pair[m];
        if (m < n0     && pm == p0) s_flag[2] = 1;   // pair handled by min-n
        if (m < n0 + 1 && pm == p1) s_flag[3] = 1;
        #pragma unroll
        for (int a = 0; a < 3; ++a) {
            int km = s_kill[3*m + a];
            if (!km) continue;
            int idx = 3*m + a;
            #pragma unroll
            for (int a2 = 0; a2 < 3; ++a2) {
                if (idx < 3*n0 + a2     && km == k0[a2]) s_flag[4 + a2] = 1;
                if (idx < 3*(n0+1) + a2 && km == k1[a2]) s_flag[7 + a2] = 1;
            }
        }
    }
    __syncthreads();

    // ---- owned-target contributions (thread 0 -> n0, thread 64 -> n0+1) ----
    if (t == 0 || t == 64) {
        const int j = t >> 6;
        const int n = n0 + j;
        int cell, pair, kk[3], best; float gx, gy, gw, gh;
        decode_target(s_targ + n*6, s_anc, cell, pair, kk, best, gx, gy, gw, gh);

        int repv = 0;
        if (!s_flag[j]) {                       // I'm this cell's representative
            float tx = gx - floorf(gx);
            float ty = gy - floorf(gy);
            float tw = __logf(gw / s_anc[2*best]   + 1e-16f);
            float th = __logf(gh / s_anc[2*best+1] + 1e-16f);
            float dx = center_x[cell] - tx;
            float dy = center_y[cell] - ty;
            float dw = width_[cell]  - tw;
            float dh = height_[cell] - th;
            atomicAdd(&s_acc[1], dx*dx);
            atomicAdd(&s_acc[2], dy*dy);
            atomicAdd(&s_acc[3], dw*dw);
            atomicAdd(&s_acc[4], dh*dh);
            atomicAdd(&s_acc[5], -flog(confidence[cell]));
            atomicAdd(&s_acc[9], 1.f);          // n_obj
            repv = 1;
        }
        s_repcell[j] = repv ? cell : -1;

        if (!s_flag[2 + j]) {                   // first occurrence of (cell,label)
            float p = pred_cls[(size_t)pair];
            atomicAdd(&s_acc[6], -flog(p) + flog(1.f - p));
        }

        float csub = 0.f, nk = 0.f;
        #pragma unroll
        for (int a = 0; a < 3; ++a) {
            int kc = kk[a];
            if (kc && !s_flag[4 + 3*j + a]) {   // first occurrence of killed cell
                csub += -flog(1.f - confidence[kc - 1]);
                nk += 1.f;
            }
        }
        if (nk != 0.f) { atomicAdd(&s_acc[7], csub); atomicAdd(&s_acc[10], nk); }
    }
    __syncthreads();

    // ---- cls base for owned representative cells (80 classes each) ----
    {
        const int j = t >> 7;                   // threads 0-127 -> rep0, 128-255 -> rep1
        const int c = t & 127;
        float v = 0.f;
        int cell = s_repcell[j];
        if (cell >= 0 && c < Cv)
            v = -flog(1.f - pred_cls[(size_t)cell * Cv + c]);
        v = wred(v);
        if ((t & 63) == 0) atomicAdd(&s_acc[8], v);
    }

    // ---- bulk: sum of -clip(log(1-conf)) over ALL cells ----
    {
        float local = 0.f;
        const float4* c4 = (const float4*)confidence;
        for (int i = blockIdx.x * NTHR + t; i < Mv/4; i += NBLK * NTHR) {
            float4 v = c4[i];
            local -= flog(1.f - v.x) + flog(1.f - v.y) + flog(1.f - v.z) + flog(1.f - v.w);
        }
        local = wred(local);
        if ((t & 63) == 0) atomicAdd(&s_acc[0], local);
    }
    __syncthreads();

    // ---- publish partials (agent-scope, device-coherent), then sentinel ----
    if (t < 11)
        __hip_atomic_store(&partials[blockIdx.x * 16 + t], s_acc[t],
                           __ATOMIC_RELAXED, __HIP_MEMORY_SCOPE_AGENT);
    __syncthreads();            // all 11 stores issued before sentinel
    if (t == 0) {
        int* sent = (int*)&partials[blockIdx.x * 16 + 11];
        __hip_atomic_store(sent, SENT_BASE | blockIdx.x,
                           __ATOMIC_RELEASE, __HIP_MEMORY_SCOPE_AGENT);
    }

    // ---- block 255: spin for all 256 sentinels, reduce, write scalar ----
    // Deadlock-free: grid (256 blk × 256 thr, 30 KB LDS) is fully co-resident
    // on 256 CUs and no other block ever waits on this one.
    if (blockIdx.x == NBLK - 1) {
        __shared__ float s_r[4][11];
        const int* sent = (const int*)&partials[t * 16 + 11];
        const int expect = SENT_BASE | t;      // poison 0xAAAAAAAA can't match
        while (__hip_atomic_load(sent, __ATOMIC_ACQUIRE,
                                 __HIP_MEMORY_SCOPE_AGENT) != expect)
            __builtin_amdgcn_s_sleep(1);

        float v[11];
        #pragma unroll
        for (int j = 0; j < 11; ++j)
            v[j] = __hip_atomic_load(&partials[t * 16 + j],
                                     __ATOMIC_RELAXED, __HIP_MEMORY_SCOPE_AGENT);
        #pragma unroll
        for (int j = 0; j < 11; ++j) v[j] = wred(v[j]);
        const int lane = t & 63, w = t >> 6;
        if (lane == 0) {
            #pragma unroll
            for (int j = 0; j < 11; ++j) s_r[w][j] = v[j];
        }
        __syncthreads();
        if (t == 0) {
            float a[11];
            #pragma unroll
            for (int j = 0; j < 11; ++j)
                a[j] = s_r[0][j] + s_r[1][j] + s_r[2][j] + s_r[3][j];
            float n_obj   = a[9];
            float n_kill  = a[10];
            float inv_obj = 1.f / n_obj;
            float n_noobj = (float)Mv - n_kill;
            float loss_coord = (a[1] + a[2] + a[3] + a[4]) * inv_obj;
            float loss_conf  = a[5] * inv_obj + 100.f * (a[0] - a[7]) / n_noobj;
            float loss_cls   = (a[8] + a[6]) * inv_obj / (float)Cv;
            out[0] = loss_coord + loss_conf + loss_cls;
        }
    }
}

extern "C" void kernel_launch(void* const* d_in, const int* in_sizes, int n_in,
                              void* d_out, int out_size, void* d_ws, size_t ws_size,
                              hipStream_t stream) {
    // setup_inputs order: 0:pred_boxes(unused) 1:pred_cls 2:center_x 3:center_y
    //                     4:width 5:height 6:confidence 7:anchors 8:target
    const float* pred_cls   = (const float*)d_in[1];
    const float* center_x   = (const float*)d_in[2];
    const float* center_y   = (const float*)d_in[3];
    const float* width_     = (const float*)d_in[4];
    const float* height_    = (const float*)d_in[5];
    const float* confidence = (const float*)d_in[6];
    const float* anchors    = (const float*)d_in[7];
    const float* target     = (const float*)d_in[8];
    float* partials = (float*)d_ws;   // 256 blocks × 16 floats = 16 KB

    fused_kernel<<<NBLK, NTHR, 0, stream>>>(pred_cls, center_x, center_y, width_,
                                            height_, confidence, anchors, target,
                                            partials, (float*)d_out);
}